// Round 1
// baseline (327.322 us; speedup 1.0000x reference)
//
#include <hip/hip_runtime.h>
#include <hip/hip_bf16.h>

// ---------------------------------------------------------------------------
// SCANCircuitV4C: the reference's output depends ONLY on the root node's final
// buffer. Stage-1 buffers have a single nonzero row (an action_embed row), so
// mod buffers are rank-1 (attn column 0 x embed row) and the comb root is a
// 2-term rank-1 sum. MLP inputs quantize to 4 (mod) + 32 (comb) configs, so
// all MLP/softmax work collapses into tiny precomputed tables.
// ---------------------------------------------------------------------------

#define NNODE 16

// ws float offsets
#define MODCOL_OFF 0       // [4][48]   attn_mod[:,0] per mod config
#define C0_OFF     192     // [32][48]  attn_comb[:,0]
#define C48_OFF    1728    // [32][48]  attn_comb[:,48]
#define DOTL_OFF   3264    // [32][4][48]  sum_q attnC[p,q]*modcol0[m][q]
#define DOTR_OFF   9408    // [32][4][48]  sum_q attnC[p,48+q]*modcol0[m][q]
#define G_OFF      15552   // [8][8]    E @ E^T
// total 15616 floats = 62464 bytes

__device__ __forceinline__ float gelu_exact(float x) {
    return 0.5f * x * (1.0f + erff(x * 0.70710678118654752f));
}

__global__ __launch_bounds__(256) void scan_precompute(
    const float* __restrict__ E,
    const float* __restrict__ mw1, const float* __restrict__ mb1,
    const float* __restrict__ mw2, const float* __restrict__ mb2,
    const float* __restrict__ mw3, const float* __restrict__ mb3,
    const float* __restrict__ cw1, const float* __restrict__ cb1,
    const float* __restrict__ cw2, const float* __restrict__ cb2,
    const float* __restrict__ cw3, const float* __restrict__ cb3,
    float* __restrict__ ws)
{
    __shared__ float sh_h1[128];
    __shared__ float sh_h2[128];
    __shared__ float sh_logits[48 * 96];
    __shared__ float sh_mc0[4][48];

    const int tid = threadIdx.x;
    const int blk = blockIdx.x;

    if (blk < 4) {
        // ---- mod config `blk`: write attn_mod[:,0] to ws. Block 0 also does G.
        if (blk == 0 && tid < 64) {
            const int i = tid >> 3, a = tid & 7;
            float s = 0.f;
            #pragma unroll
            for (int d = 0; d < 32; ++d) s += E[i * 32 + d] * E[a * 32 + d];
            ws[G_OFF + tid] = s;
        }
        const int cnt = blk >> 1, sub = blk & 1;
        const float f0 = (float)cnt / 48.0f;
        const float f1 = (sub == 0) ? 1.0f : 0.0f;
        const float f2 = (sub == 1) ? 1.0f : 0.0f;
        if (tid < 128) {
            float v = mw1[tid * 3 + 0] * f0 + mw1[tid * 3 + 1] * f1 + mw1[tid * 3 + 2] * f2 + mb1[tid];
            sh_h1[tid] = gelu_exact(v);
        }
        __syncthreads();
        if (tid < 128) {
            float v = mb2[tid];
            const float* wr = mw2 + tid * 128;
            for (int i = 0; i < 128; ++i) v += wr[i] * sh_h1[i];
            sh_h2[tid] = gelu_exact(v);
        }
        __syncthreads();
        for (int o = tid; o < 2304; o += 256) {
            float v = mb3[o];
            const float* wr = mw3 + o * 128;
            for (int i = 0; i < 128; ++i) v += wr[i] * sh_h2[i];
            sh_logits[o] = v;
        }
        __syncthreads();
        if (tid < 48) {
            const float* row = sh_logits + tid * 48;
            float mx = row[0];
            for (int q = 1; q < 48; ++q) mx = fmaxf(mx, row[q]);
            float s = 0.f;
            for (int q = 0; q < 48; ++q) s += expf(row[q] - mx);
            ws[MODCOL_OFF + blk * 48 + tid] = expf(row[0] - mx) / s;
        }
        return;
    }

    // ---- comb config c: need full softmaxed attn + dots against mod columns.
    // Mod columns are recomputed locally (cheap) to avoid a cross-block dep.
    const int c = blk - 4;
    const int csub = c & 1;
    const int rc = (c >> 1) & 3;
    const int lc = (c >> 3) & 3;

    for (int m = 0; m < 4; ++m) {
        const int mcnt = m >> 1, msub = m & 1;
        const float f0 = (float)mcnt / 48.0f;
        const float f1 = (msub == 0) ? 1.0f : 0.0f;
        const float f2 = (msub == 1) ? 1.0f : 0.0f;
        if (tid < 128) {
            float v = mw1[tid * 3 + 0] * f0 + mw1[tid * 3 + 1] * f1 + mw1[tid * 3 + 2] * f2 + mb1[tid];
            sh_h1[tid] = gelu_exact(v);
        }
        __syncthreads();
        if (tid < 128) {
            float v = mb2[tid];
            const float* wr = mw2 + tid * 128;
            for (int i = 0; i < 128; ++i) v += wr[i] * sh_h1[i];
            sh_h2[tid] = gelu_exact(v);
        }
        __syncthreads();
        for (int o = tid; o < 2304; o += 256) {
            float v = mb3[o];
            const float* wr = mw3 + o * 128;
            for (int i = 0; i < 128; ++i) v += wr[i] * sh_h2[i];
            sh_logits[o] = v;
        }
        __syncthreads();
        if (tid < 48) {
            const float* row = sh_logits + tid * 48;
            float mx = row[0];
            for (int q = 1; q < 48; ++q) mx = fmaxf(mx, row[q]);
            float s = 0.f;
            for (int q = 0; q < 48; ++q) s += expf(row[q] - mx);
            sh_mc0[m][tid] = expf(row[0] - mx) / s;
        }
        __syncthreads();
    }

    {
        const float f0 = (float)lc / 48.0f;
        const float f1 = (float)rc / 48.0f;
        const float f2 = (csub == 0) ? 1.0f : 0.0f;
        const float f3 = (csub == 1) ? 1.0f : 0.0f;
        if (tid < 128) {
            float v = cw1[tid * 4 + 0] * f0 + cw1[tid * 4 + 1] * f1 +
                      cw1[tid * 4 + 2] * f2 + cw1[tid * 4 + 3] * f3 + cb1[tid];
            sh_h1[tid] = gelu_exact(v);
        }
        __syncthreads();
        if (tid < 128) {
            float v = cb2[tid];
            const float* wr = cw2 + tid * 128;
            for (int i = 0; i < 128; ++i) v += wr[i] * sh_h1[i];
            sh_h2[tid] = gelu_exact(v);
        }
        __syncthreads();
        for (int o = tid; o < 4608; o += 256) {
            float v = cb3[o];
            const float* wr = cw3 + o * 128;
            for (int i = 0; i < 128; ++i) v += wr[i] * sh_h2[i];
            sh_logits[o] = v;
        }
        __syncthreads();
        if (tid < 48) {
            float* row = sh_logits + tid * 96;
            float mx = row[0];
            for (int q = 1; q < 96; ++q) mx = fmaxf(mx, row[q]);
            float s = 0.f;
            for (int q = 0; q < 96; ++q) s += expf(row[q] - mx);
            const float inv = 1.0f / s;
            for (int q = 0; q < 96; ++q) row[q] = expf(row[q] - mx) * inv;
            ws[C0_OFF + c * 48 + tid]  = row[0];
            ws[C48_OFF + c * 48 + tid] = row[48];
        }
        __syncthreads();
        if (tid < 192) {
            const int m = tid / 48, p = tid % 48;
            const float* row = sh_logits + p * 96;
            float sL = 0.f, sR = 0.f;
            for (int q = 0; q < 48; ++q) {
                sL += row[q]      * sh_mc0[m][q];
                sR += row[48 + q] * sh_mc0[m][q];
            }
            ws[DOTL_OFF + (c * 4 + m) * 48 + p] = sL;
            ws[DOTR_OFF + (c * 4 + m) * 48 + p] = sR;
        }
    }
}

__global__ __launch_bounds__(384) void scan_output(
    const int* __restrict__ cats, const int* __restrict__ subs,
    const int* __restrict__ mask, const int* __restrict__ cl,
    const int* __restrict__ cr,
    const float* __restrict__ ws,
    float* __restrict__ out)
{
    __shared__ int sc[NNODE], ss[NNODE], sm[NNODE], sl[NNODE], sr[NNODE];
    __shared__ int s_dec[7];  // modeL, modeR, offL, offR, aidL, aidR, count0
    __shared__ float s_G[64];

    const int b = blockIdx.x;
    const int tid = threadIdx.x;
    if (tid < NNODE) {
        sc[tid] = cats[b * NNODE + tid];
        ss[tid] = subs[b * NNODE + tid];
        sm[tid] = mask[b * NNODE + tid];
        sl[tid] = cl[b * NNODE + tid];
        sr[tid] = cr[b * NNODE + tid];
    } else if (tid >= 64 && tid < 128) {
        s_G[tid - 64] = ws[G_OFF + tid - 64];
    }
    __syncthreads();

    if (tid == 0) {
        auto clampN  = [](int x) { return x < 0 ? 0 : (x > NNODE - 1 ? NNODE - 1 : x); };
        auto clamp01 = [](int x) { return x < 0 ? 0 : (x > 1 ? 1 : x); };
        auto clampA  = [](int x) { return x < 0 ? 0 : (x > 7 ? 7 : x); };
        auto PRIM = [&](int n) { return (sc[n] == 0) && (sm[n] != 0); };
        auto MODM = [&](int n) { return (sc[n] == 1) && (sm[n] != 0); };
        auto AID  = [&](int n) { return clampA(ss[n] + 1); };

        int modeL = 0, modeR = 0, offL = 0, offR = 0, aidL = 0, aidR = 0, count0 = 0;
        const int  cat0 = sc[0];
        const bool msk0 = sm[0] != 0;
        const int  sub0 = clamp01(ss[0]);
        const int  cl0  = clampN(sl[0]);
        const int  cr0  = clampN(sr[0]);

        if (cat0 == 2 && msk0) {
            // comb root: children come from post-mod (stage-2) buffers/counts
            auto cnt2 = [&](int n) -> int {
                if (MODM(n)) {
                    int c1 = PRIM(clampN(sl[n])) ? 1 : 0;
                    int f  = clamp01(ss[n]) ? 3 : 2;
                    int v  = c1 * f;
                    return v > 48 ? 48 : v;
                }
                return PRIM(n) ? 1 : 0;
            };
            const int l = cl0, r = cr0;
            const int lcc = cnt2(l), rcc = cnt2(r);
            const int cidx = (lcc * 4 + rcc) * 2 + sub0;
            count0 = lcc + rcc; if (count0 > 48) count0 = 48;
            if (MODM(l)) {
                const int g = clampN(sl[l]);
                if (PRIM(g)) {  // mod child with nonzero source
                    modeL = 1; aidL = AID(g);
                    const int mcfg = 2 + clamp01(ss[l]);  // child_cnt == 1 here
                    offL = DOTL_OFF + (cidx * 4 + mcfg) * 48;
                }
            } else if (PRIM(l)) {
                modeL = 1; aidL = AID(l);
                offL = C0_OFF + cidx * 48;
            }
            if (MODM(r)) {
                const int g = clampN(sl[r]);
                if (PRIM(g)) {
                    modeR = 1; aidR = AID(g);
                    const int mcfg = 2 + clamp01(ss[r]);
                    offR = DOTR_OFF + (cidx * 4 + mcfg) * 48;
                }
            } else if (PRIM(r)) {
                modeR = 1; aidR = AID(r);
                offR = C48_OFF + cidx * 48;
            }
        } else if (cat0 == 1 && msk0) {
            // mod root
            const int ch = cl0;
            const int c1 = PRIM(ch) ? 1 : 0;
            count0 = c1 * (sub0 ? 3 : 2); if (count0 > 48) count0 = 48;
            if (c1) {
                modeL = 1; aidL = AID(ch);
                offL = MODCOL_OFF + (2 + sub0) * 48;  // mcfg = 1*2 + sub0
            }
        } else if (cat0 == 0 && msk0) {
            // prim root: only row p==0 nonzero
            modeL = 2; aidL = AID(0); count0 = 1;
        }
        s_dec[0] = modeL; s_dec[1] = modeR; s_dec[2] = offL; s_dec[3] = offR;
        s_dec[4] = aidL;  s_dec[5] = aidR;  s_dec[6] = count0;
    }
    __syncthreads();

    const int p = tid >> 3, a = tid & 7;
    const int modeL = s_dec[0], modeR = s_dec[1];
    float v = 0.f;
    if (modeL == 1)       v += ws[s_dec[2] + p] * s_G[s_dec[4] * 8 + a];
    else if (modeL == 2)  { if (p == 0) v = s_G[s_dec[4] * 8 + a]; }
    if (modeR == 1)       v += ws[s_dec[3] + p] * s_G[s_dec[5] * 8 + a];
    if (a == 0 && p >= s_dec[6]) v += 8.0f;
    out[b * 384 + tid] = v;
}

extern "C" void kernel_launch(void* const* d_in, const int* in_sizes, int n_in,
                              void* d_out, int out_size, void* d_ws, size_t ws_size,
                              hipStream_t stream) {
    const int* cats = (const int*)d_in[0];
    const int* subs = (const int*)d_in[1];
    const int* mask = (const int*)d_in[2];
    const int* cl   = (const int*)d_in[3];
    const int* cr   = (const int*)d_in[4];
    const float* E   = (const float*)d_in[5];
    const float* mw1 = (const float*)d_in[6];
    const float* mb1 = (const float*)d_in[7];
    const float* mw2 = (const float*)d_in[8];
    const float* mb2 = (const float*)d_in[9];
    const float* mw3 = (const float*)d_in[10];
    const float* mb3 = (const float*)d_in[11];
    const float* cw1 = (const float*)d_in[12];
    const float* cb1 = (const float*)d_in[13];
    const float* cw2 = (const float*)d_in[14];
    const float* cb2 = (const float*)d_in[15];
    const float* cw3 = (const float*)d_in[16];
    const float* cb3 = (const float*)d_in[17];
    float* ws  = (float*)d_ws;
    float* out = (float*)d_out;
    const int B = in_sizes[0] / NNODE;

    scan_precompute<<<36, 256, 0, stream>>>(E, mw1, mb1, mw2, mb2, mw3, mb3,
                                            cw1, cb1, cw2, cb2, cw3, cb3, ws);
    scan_output<<<B, 384, 0, stream>>>(cats, subs, mask, cl, cr, ws, out);
}

// Round 2
// 111.134 us; speedup vs baseline: 2.9453x; 2.9453x over previous
//
#include <hip/hip_runtime.h>
#include <hip/hip_bf16.h>
#include <float.h>

// ---------------------------------------------------------------------------
// SCANCircuitV4C: output depends only on the root buffer; MLP inputs quantize
// to 4 mod + 32 comb configs -> precompute tiny tables, then table-lookup per
// batch. R1: re-parallelized table build (229 + 1536 blocks instead of 36)
// with float4 row dots and LDS softmax reduction.
// ---------------------------------------------------------------------------

#define NNODE 16

// ws float offsets
#define MODCOL_OFF 0       // [4][48]      attn_mod[:,0] per mod config (idx [m*48+p])
#define C0_OFF     192     // [32][48]     attn_comb[p,0]
#define C48_OFF    1728    // [32][48]     attn_comb[p,48]
#define DOTL_OFF   3264    // [32][4][48]  sum_q attnC[p,q]   * modcol0[m][q]
#define DOTR_OFF   9408    // [32][4][48]  sum_q attnC[p,48+q]* modcol0[m][q]
#define G_OFF      15552   // [8][8]       E @ E^T
#define H2_OFF     15616   // [32][128]    comb h2 per config
// total 19712 floats = 78848 bytes

__device__ __forceinline__ float gelu_exact(float x) {
    return 0.5f * x * (1.0f + erff(x * 0.70710678118654752f));
}

__device__ __forceinline__ float dot128(const float* __restrict__ w,
                                        const float* __restrict__ h) {
    const float4* w4 = (const float4*)w;
    float s = 0.f;
    #pragma unroll
    for (int i = 0; i < 32; ++i) {
        float4 v = w4[i];
        s += v.x * h[4 * i + 0] + v.y * h[4 * i + 1] +
             v.z * h[4 * i + 2] + v.w * h[4 * i + 3];
    }
    return s;
}

// Kernel A: blocks 0..191 -> (mod config m, row p) attention col-0;
//           blocks 192..223 -> comb h2 per config; block 224 -> Gram matrix.
__global__ __launch_bounds__(128) void scan_tables_a(
    const float* __restrict__ E,
    const float* __restrict__ mw1, const float* __restrict__ mb1,
    const float* __restrict__ mw2, const float* __restrict__ mb2,
    const float* __restrict__ mw3, const float* __restrict__ mb3,
    const float* __restrict__ cw1, const float* __restrict__ cb1,
    const float* __restrict__ cw2, const float* __restrict__ cb2,
    float* __restrict__ ws)
{
    __shared__ float h1[128];
    __shared__ float h2s[128];
    __shared__ float lg[48];

    const int tid = threadIdx.x;
    const int blk = blockIdx.x;

    if (blk < 192) {
        const int m = blk / 48, p = blk % 48;
        const int cnt = m >> 1, sub = m & 1;
        const float f0 = (float)cnt / 48.0f;
        const float f1 = (sub == 0) ? 1.0f : 0.0f;
        const float f2 = (sub == 1) ? 1.0f : 0.0f;
        h1[tid] = gelu_exact(mw1[tid * 3 + 0] * f0 + mw1[tid * 3 + 1] * f1 +
                             mw1[tid * 3 + 2] * f2 + mb1[tid]);
        __syncthreads();
        h2s[tid] = gelu_exact(dot128(mw2 + tid * 128, h1) + mb2[tid]);
        __syncthreads();
        if (tid < 48)
            lg[tid] = dot128(mw3 + (p * 48 + tid) * 128, h2s) + mb3[p * 48 + tid];
        __syncthreads();
        if (tid == 0) {
            float mx = lg[0];
            for (int q = 1; q < 48; ++q) mx = fmaxf(mx, lg[q]);
            float s = 0.f;
            for (int q = 0; q < 48; ++q) s += expf(lg[q] - mx);
            ws[MODCOL_OFF + m * 48 + p] = expf(lg[0] - mx) / s;
        }
        return;
    }
    if (blk < 224) {
        const int c = blk - 192;
        const int csub = c & 1;
        const int rc = (c >> 1) & 3;
        const int lc = (c >> 3) & 3;
        const float f0 = (float)lc / 48.0f;
        const float f1 = (float)rc / 48.0f;
        const float f2 = (csub == 0) ? 1.0f : 0.0f;
        const float f3 = (csub == 1) ? 1.0f : 0.0f;
        h1[tid] = gelu_exact(cw1[tid * 4 + 0] * f0 + cw1[tid * 4 + 1] * f1 +
                             cw1[tid * 4 + 2] * f2 + cw1[tid * 4 + 3] * f3 + cb1[tid]);
        __syncthreads();
        ws[H2_OFF + c * 128 + tid] =
            gelu_exact(dot128(cw2 + tid * 128, h1) + cb2[tid]);
        return;
    }
    // Gram matrix
    if (tid < 64) {
        const int i = tid >> 3, a = tid & 7;
        float s = 0.f;
        #pragma unroll
        for (int d = 0; d < 32; ++d) s += E[i * 32 + d] * E[a * 32 + d];
        ws[G_OFF + tid] = s;
    }
}

// Kernel B: one block per (comb config c, row p). 96 logit dots, LDS softmax,
// write C0/C48 and the 8 dot products against mod columns.
__global__ __launch_bounds__(128) void scan_tables_b(
    const float* __restrict__ cw3, const float* __restrict__ cb3,
    float* __restrict__ ws)
{
    __shared__ float h2s[128];
    __shared__ float pr[96];    // exp(logit - mx)
    __shared__ float mc[192];   // mod columns [4][48]
    __shared__ float red[128];

    const int tid = threadIdx.x;
    const int c = blockIdx.x / 48;
    const int p = blockIdx.x % 48;

    h2s[tid] = ws[H2_OFF + c * 128 + tid];
    if (tid < 64) mc[tid] = ws[MODCOL_OFF + tid];
    else if (tid < 128 && tid >= 64) { if (tid - 64 < 128) mc[64 + (tid - 64)] = ws[MODCOL_OFF + 64 + (tid - 64)]; }
    if (tid < 64) mc[128 + tid] = ws[MODCOL_OFF + 128 + tid];
    __syncthreads();

    float lv = -FLT_MAX;
    if (tid < 96)
        lv = dot128(cw3 + (p * 96 + tid) * 128, h2s) + cb3[p * 96 + tid];

    // max reduce over 96 values
    red[tid] = lv;
    __syncthreads();
    for (int s = 64; s > 0; s >>= 1) {
        if (tid < s) red[tid] = fmaxf(red[tid], red[tid + s]);
        __syncthreads();
    }
    const float mx = red[0];
    __syncthreads();

    float ev = (tid < 96) ? expf(lv - mx) : 0.f;
    if (tid < 96) pr[tid] = ev;
    red[tid] = ev;
    __syncthreads();
    for (int s = 64; s > 0; s >>= 1) {
        if (tid < s) red[tid] += red[tid + s];
        __syncthreads();
    }
    const float inv = 1.0f / red[0];

    if (tid == 0) {
        ws[C0_OFF + c * 48 + p]  = pr[0]  * inv;
        ws[C48_OFF + c * 48 + p] = pr[48] * inv;
    }
    if (tid < 8) {
        const int m = tid & 3;
        const int side = tid >> 2;   // 0 = L, 1 = R
        const float* q0 = pr + side * 48;
        float s = 0.f;
        #pragma unroll
        for (int q = 0; q < 48; ++q) s += q0[q] * mc[m * 48 + q];
        const int off = (side == 0 ? DOTL_OFF : DOTR_OFF) + (c * 4 + m) * 48 + p;
        ws[off] = s * inv;
    }
}

__global__ __launch_bounds__(384) void scan_output(
    const int* __restrict__ cats, const int* __restrict__ subs,
    const int* __restrict__ mask, const int* __restrict__ cl,
    const int* __restrict__ cr,
    const float* __restrict__ ws,
    float* __restrict__ out)
{
    __shared__ int sc[NNODE], ss[NNODE], sm[NNODE], sl[NNODE], sr[NNODE];
    __shared__ int s_dec[7];  // modeL, modeR, offL, offR, aidL, aidR, count0
    __shared__ float s_G[64];

    const int b = blockIdx.x;
    const int tid = threadIdx.x;
    if (tid < NNODE) {
        sc[tid] = cats[b * NNODE + tid];
        ss[tid] = subs[b * NNODE + tid];
        sm[tid] = mask[b * NNODE + tid];
        sl[tid] = cl[b * NNODE + tid];
        sr[tid] = cr[b * NNODE + tid];
    } else if (tid >= 64 && tid < 128) {
        s_G[tid - 64] = ws[G_OFF + tid - 64];
    }
    __syncthreads();

    if (tid == 0) {
        auto clampN  = [](int x) { return x < 0 ? 0 : (x > NNODE - 1 ? NNODE - 1 : x); };
        auto clamp01 = [](int x) { return x < 0 ? 0 : (x > 1 ? 1 : x); };
        auto clampA  = [](int x) { return x < 0 ? 0 : (x > 7 ? 7 : x); };
        auto PRIM = [&](int n) { return (sc[n] == 0) && (sm[n] != 0); };
        auto MODM = [&](int n) { return (sc[n] == 1) && (sm[n] != 0); };
        auto AID  = [&](int n) { return clampA(ss[n] + 1); };

        int modeL = 0, modeR = 0, offL = 0, offR = 0, aidL = 0, aidR = 0, count0 = 0;
        const int  cat0 = sc[0];
        const bool msk0 = sm[0] != 0;
        const int  sub0 = clamp01(ss[0]);
        const int  cl0  = clampN(sl[0]);
        const int  cr0  = clampN(sr[0]);

        if (cat0 == 2 && msk0) {
            // comb root: children come from post-mod (stage-2) buffers/counts
            auto cnt2 = [&](int n) -> int {
                if (MODM(n)) {
                    int c1 = PRIM(clampN(sl[n])) ? 1 : 0;
                    int f  = clamp01(ss[n]) ? 3 : 2;
                    int v  = c1 * f;
                    return v > 48 ? 48 : v;
                }
                return PRIM(n) ? 1 : 0;
            };
            const int l = cl0, r = cr0;
            const int lcc = cnt2(l), rcc = cnt2(r);
            const int cidx = (lcc * 4 + rcc) * 2 + sub0;
            count0 = lcc + rcc; if (count0 > 48) count0 = 48;
            if (MODM(l)) {
                const int g = clampN(sl[l]);
                if (PRIM(g)) {  // mod child with nonzero source
                    modeL = 1; aidL = AID(g);
                    const int mcfg = 2 + clamp01(ss[l]);  // child_cnt == 1 here
                    offL = DOTL_OFF + (cidx * 4 + mcfg) * 48;
                }
            } else if (PRIM(l)) {
                modeL = 1; aidL = AID(l);
                offL = C0_OFF + cidx * 48;
            }
            if (MODM(r)) {
                const int g = clampN(sl[r]);
                if (PRIM(g)) {
                    modeR = 1; aidR = AID(g);
                    const int mcfg = 2 + clamp01(ss[r]);
                    offR = DOTR_OFF + (cidx * 4 + mcfg) * 48;
                }
            } else if (PRIM(r)) {
                modeR = 1; aidR = AID(r);
                offR = C48_OFF + cidx * 48;
            }
        } else if (cat0 == 1 && msk0) {
            // mod root
            const int ch = cl0;
            const int c1 = PRIM(ch) ? 1 : 0;
            count0 = c1 * (sub0 ? 3 : 2); if (count0 > 48) count0 = 48;
            if (c1) {
                modeL = 1; aidL = AID(ch);
                offL = MODCOL_OFF + (2 + sub0) * 48;  // mcfg = 1*2 + sub0
            }
        } else if (cat0 == 0 && msk0) {
            // prim root: only row p==0 nonzero
            modeL = 2; aidL = AID(0); count0 = 1;
        }
        s_dec[0] = modeL; s_dec[1] = modeR; s_dec[2] = offL; s_dec[3] = offR;
        s_dec[4] = aidL;  s_dec[5] = aidR;  s_dec[6] = count0;
    }
    __syncthreads();

    const int p = tid >> 3, a = tid & 7;
    const int modeL = s_dec[0], modeR = s_dec[1];
    float v = 0.f;
    if (modeL == 1)       v += ws[s_dec[2] + p] * s_G[s_dec[4] * 8 + a];
    else if (modeL == 2)  { if (p == 0) v = s_G[s_dec[4] * 8 + a]; }
    if (modeR == 1)       v += ws[s_dec[3] + p] * s_G[s_dec[5] * 8 + a];
    if (a == 0 && p >= s_dec[6]) v += 8.0f;
    out[b * 384 + tid] = v;
}

extern "C" void kernel_launch(void* const* d_in, const int* in_sizes, int n_in,
                              void* d_out, int out_size, void* d_ws, size_t ws_size,
                              hipStream_t stream) {
    const int* cats = (const int*)d_in[0];
    const int* subs = (const int*)d_in[1];
    const int* mask = (const int*)d_in[2];
    const int* cl   = (const int*)d_in[3];
    const int* cr   = (const int*)d_in[4];
    const float* E   = (const float*)d_in[5];
    const float* mw1 = (const float*)d_in[6];
    const float* mb1 = (const float*)d_in[7];
    const float* mw2 = (const float*)d_in[8];
    const float* mb2 = (const float*)d_in[9];
    const float* mw3 = (const float*)d_in[10];
    const float* mb3 = (const float*)d_in[11];
    const float* cw1 = (const float*)d_in[12];
    const float* cb1 = (const float*)d_in[13];
    const float* cw2 = (const float*)d_in[14];
    const float* cb2 = (const float*)d_in[15];
    const float* cw3 = (const float*)d_in[16];
    const float* cb3 = (const float*)d_in[17];
    float* ws  = (float*)d_ws;
    float* out = (float*)d_out;
    const int B = in_sizes[0] / NNODE;

    scan_tables_a<<<225, 128, 0, stream>>>(E, mw1, mb1, mw2, mb2, mw3, mb3,
                                           cw1, cb1, cw2, cb2, ws);
    scan_tables_b<<<32 * 48, 128, 0, stream>>>(cw3, cb3, ws);
    scan_output<<<B, 384, 0, stream>>>(cats, subs, mask, cl, cr, ws, out);
}

// Round 3
// 107.543 us; speedup vs baseline: 3.0436x; 1.0334x over previous
//
#include <hip/hip_runtime.h>
#include <hip/hip_bf16.h>
#include <float.h>

// ---------------------------------------------------------------------------
// SCANCircuitV4C: output depends only on the root buffer; MLP inputs quantize
// to 4 mod + 32 comb configs -> precompute tiny tables, then table-lookup per
// batch. R2: kernel B rewritten with quad-coalesced row dots (64B segments),
// shuffle softmax, and p-major block order for L2 slice sharing.
// ---------------------------------------------------------------------------

#define NNODE 16

// ws float offsets
#define MODCOL_OFF 0       // [4][48]      attn_mod[:,0] per mod config (idx [m*48+p])
#define C0_OFF     192     // [32][48]     attn_comb[p,0]
#define C48_OFF    1728    // [32][48]     attn_comb[p,48]
#define DOTL_OFF   3264    // [32][4][48]  sum_q attnC[p,q]   * modcol0[m][q]
#define DOTR_OFF   9408    // [32][4][48]  sum_q attnC[p,48+q]* modcol0[m][q]
#define G_OFF      15552   // [8][8]       E @ E^T
#define H2_OFF     15616   // [32][128]    comb h2 per config
// total 19712 floats = 78848 bytes

__device__ __forceinline__ float gelu_exact(float x) {
    return 0.5f * x * (1.0f + erff(x * 0.70710678118654752f));
}

__device__ __forceinline__ float dot128(const float* __restrict__ w,
                                        const float* __restrict__ h) {
    const float4* w4 = (const float4*)w;
    float s = 0.f;
    #pragma unroll
    for (int i = 0; i < 32; ++i) {
        float4 v = w4[i];
        s += v.x * h[4 * i + 0] + v.y * h[4 * i + 1] +
             v.z * h[4 * i + 2] + v.w * h[4 * i + 3];
    }
    return s;
}

// Kernel A: blocks 0..191 -> (mod config m, row p) attention col-0;
//           blocks 192..223 -> comb h2 per config; block 224 -> Gram matrix.
__global__ __launch_bounds__(128) void scan_tables_a(
    const float* __restrict__ E,
    const float* __restrict__ mw1, const float* __restrict__ mb1,
    const float* __restrict__ mw2, const float* __restrict__ mb2,
    const float* __restrict__ mw3, const float* __restrict__ mb3,
    const float* __restrict__ cw1, const float* __restrict__ cb1,
    const float* __restrict__ cw2, const float* __restrict__ cb2,
    float* __restrict__ ws)
{
    __shared__ float h1[128];
    __shared__ float h2s[128];
    __shared__ float lg[48];

    const int tid = threadIdx.x;
    const int blk = blockIdx.x;

    if (blk < 192) {
        const int m = blk / 48, p = blk % 48;
        const int cnt = m >> 1, sub = m & 1;
        const float f0 = (float)cnt / 48.0f;
        const float f1 = (sub == 0) ? 1.0f : 0.0f;
        const float f2 = (sub == 1) ? 1.0f : 0.0f;
        h1[tid] = gelu_exact(mw1[tid * 3 + 0] * f0 + mw1[tid * 3 + 1] * f1 +
                             mw1[tid * 3 + 2] * f2 + mb1[tid]);
        __syncthreads();
        h2s[tid] = gelu_exact(dot128(mw2 + tid * 128, h1) + mb2[tid]);
        __syncthreads();
        if (tid < 48)
            lg[tid] = dot128(mw3 + (p * 48 + tid) * 128, h2s) + mb3[p * 48 + tid];
        __syncthreads();
        if (tid == 0) {
            float mx = lg[0];
            for (int q = 1; q < 48; ++q) mx = fmaxf(mx, lg[q]);
            float s = 0.f;
            for (int q = 0; q < 48; ++q) s += expf(lg[q] - mx);
            ws[MODCOL_OFF + m * 48 + p] = expf(lg[0] - mx) / s;
        }
        return;
    }
    if (blk < 224) {
        const int c = blk - 192;
        const int csub = c & 1;
        const int rc = (c >> 1) & 3;
        const int lc = (c >> 3) & 3;
        const float f0 = (float)lc / 48.0f;
        const float f1 = (float)rc / 48.0f;
        const float f2 = (csub == 0) ? 1.0f : 0.0f;
        const float f3 = (csub == 1) ? 1.0f : 0.0f;
        h1[tid] = gelu_exact(cw1[tid * 4 + 0] * f0 + cw1[tid * 4 + 1] * f1 +
                             cw1[tid * 4 + 2] * f2 + cw1[tid * 4 + 3] * f3 + cb1[tid]);
        __syncthreads();
        ws[H2_OFF + c * 128 + tid] =
            gelu_exact(dot128(cw2 + tid * 128, h1) + cb2[tid]);
        return;
    }
    // Gram matrix
    if (tid < 64) {
        const int i = tid >> 3, a = tid & 7;
        float s = 0.f;
        #pragma unroll
        for (int d = 0; d < 32; ++d) s += E[i * 32 + d] * E[a * 32 + d];
        ws[G_OFF + tid] = s;
    }
}

// Kernel B: one block per (row p, comb config c), blockIdx = p*32 + c so that
// 32 consecutive blocks share the same 48KB cw3 slice (L2 locality).
// Quad-coalesced logit dots + shuffle softmax.
__global__ __launch_bounds__(128, 4) void scan_tables_b(
    const float* __restrict__ cw3, const float* __restrict__ cb3,
    float* __restrict__ ws)
{
    __shared__ float h2s[128];
    __shared__ float mc[192];   // mod columns [4][48]
    __shared__ float lg[96];    // raw logits
    __shared__ float pr[96];    // exp(logit - mx)
    __shared__ float red[4];

    const int tid = threadIdx.x;
    const int p = blockIdx.x >> 5;
    const int c = blockIdx.x & 31;

    h2s[tid] = ws[H2_OFF + c * 128 + tid];
    for (int i = tid; i < 192; i += 128) mc[i] = ws[MODCOL_OFF + i];
    __syncthreads();

    // --- logits: 4 lanes per row, 3 passes of 32 rows. Lane j of a quad
    // loads float4 indices j, 4+j, ..., 28+j -> 64B contiguous per quad.
    const int j = tid & 3;
    const int rbase = tid >> 2;            // 0..31
    const float4* h24 = (const float4*)h2s;
    #pragma unroll
    for (int o = 0; o < 3; ++o) {
        const int r = o * 32 + rbase;
        const float4* w4 = (const float4*)(cw3 + (p * 96 + r) * 128);
        float s = 0.f;
        #pragma unroll
        for (int i = 0; i < 8; ++i) {
            const int f4i = i * 4 + j;
            float4 w = w4[f4i];
            float4 h = h24[f4i];
            s += w.x * h.x + w.y * h.y + w.z * h.z + w.w * h.w;
        }
        s += __shfl_xor(s, 1);
        s += __shfl_xor(s, 2);
        if (j == 0) lg[r] = s;
    }
    __syncthreads();

    // --- softmax over 96 (2 waves; lanes beyond 96 padded)
    const int wv = tid >> 6;
    float lv = (tid < 96) ? (lg[tid] + cb3[p * 96 + tid]) : -FLT_MAX;
    float m = lv;
    #pragma unroll
    for (int d = 32; d > 0; d >>= 1) m = fmaxf(m, __shfl_xor(m, d));
    if ((tid & 63) == 0) red[wv] = m;
    __syncthreads();
    const float mx = fmaxf(red[0], red[1]);

    float ev = (tid < 96) ? expf(lv - mx) : 0.f;
    if (tid < 96) pr[tid] = ev;
    float sum = ev;
    #pragma unroll
    for (int d = 32; d > 0; d >>= 1) sum += __shfl_xor(sum, d);
    if ((tid & 63) == 0) red[2 + wv] = sum;
    __syncthreads();
    const float inv = 1.0f / (red[2] + red[3]);

    if (tid == 0) {
        ws[C0_OFF + c * 48 + p]  = pr[0]  * inv;
        ws[C48_OFF + c * 48 + p] = pr[48] * inv;
    }
    if (tid < 8) {
        const int mm = tid & 3;
        const int side = tid >> 2;   // 0 = L, 1 = R
        const float* q0 = pr + side * 48;
        const float* mr = mc + mm * 48;
        float s = 0.f;
        #pragma unroll
        for (int q = 0; q < 48; ++q) s += q0[q] * mr[q];
        const int off = (side == 0 ? DOTL_OFF : DOTR_OFF) + (c * 4 + mm) * 48 + p;
        ws[off] = s * inv;
    }
}

__global__ __launch_bounds__(384) void scan_output(
    const int* __restrict__ cats, const int* __restrict__ subs,
    const int* __restrict__ mask, const int* __restrict__ cl,
    const int* __restrict__ cr,
    const float* __restrict__ ws,
    float* __restrict__ out)
{
    __shared__ int sc[NNODE], ss[NNODE], sm[NNODE], sl[NNODE], sr[NNODE];
    __shared__ int s_dec[7];  // modeL, modeR, offL, offR, aidL, aidR, count0
    __shared__ float s_G[64];

    const int b = blockIdx.x;
    const int tid = threadIdx.x;
    if (tid < NNODE) {
        sc[tid] = cats[b * NNODE + tid];
        ss[tid] = subs[b * NNODE + tid];
        sm[tid] = mask[b * NNODE + tid];
        sl[tid] = cl[b * NNODE + tid];
        sr[tid] = cr[b * NNODE + tid];
    } else if (tid >= 64 && tid < 128) {
        s_G[tid - 64] = ws[G_OFF + tid - 64];
    }
    __syncthreads();

    if (tid == 0) {
        auto clampN  = [](int x) { return x < 0 ? 0 : (x > NNODE - 1 ? NNODE - 1 : x); };
        auto clamp01 = [](int x) { return x < 0 ? 0 : (x > 1 ? 1 : x); };
        auto clampA  = [](int x) { return x < 0 ? 0 : (x > 7 ? 7 : x); };
        auto PRIM = [&](int n) { return (sc[n] == 0) && (sm[n] != 0); };
        auto MODM = [&](int n) { return (sc[n] == 1) && (sm[n] != 0); };
        auto AID  = [&](int n) { return clampA(ss[n] + 1); };

        int modeL = 0, modeR = 0, offL = 0, offR = 0, aidL = 0, aidR = 0, count0 = 0;
        const int  cat0 = sc[0];
        const bool msk0 = sm[0] != 0;
        const int  sub0 = clamp01(ss[0]);
        const int  cl0  = clampN(sl[0]);
        const int  cr0  = clampN(sr[0]);

        if (cat0 == 2 && msk0) {
            // comb root: children come from post-mod (stage-2) buffers/counts
            auto cnt2 = [&](int n) -> int {
                if (MODM(n)) {
                    int c1 = PRIM(clampN(sl[n])) ? 1 : 0;
                    int f  = clamp01(ss[n]) ? 3 : 2;
                    int v  = c1 * f;
                    return v > 48 ? 48 : v;
                }
                return PRIM(n) ? 1 : 0;
            };
            const int l = cl0, r = cr0;
            const int lcc = cnt2(l), rcc = cnt2(r);
            const int cidx = (lcc * 4 + rcc) * 2 + sub0;
            count0 = lcc + rcc; if (count0 > 48) count0 = 48;
            if (MODM(l)) {
                const int g = clampN(sl[l]);
                if (PRIM(g)) {  // mod child with nonzero source
                    modeL = 1; aidL = AID(g);
                    const int mcfg = 2 + clamp01(ss[l]);  // child_cnt == 1 here
                    offL = DOTL_OFF + (cidx * 4 + mcfg) * 48;
                }
            } else if (PRIM(l)) {
                modeL = 1; aidL = AID(l);
                offL = C0_OFF + cidx * 48;
            }
            if (MODM(r)) {
                const int g = clampN(sl[r]);
                if (PRIM(g)) {
                    modeR = 1; aidR = AID(g);
                    const int mcfg = 2 + clamp01(ss[r]);
                    offR = DOTR_OFF + (cidx * 4 + mcfg) * 48;
                }
            } else if (PRIM(r)) {
                modeR = 1; aidR = AID(r);
                offR = C48_OFF + cidx * 48;
            }
        } else if (cat0 == 1 && msk0) {
            // mod root
            const int ch = cl0;
            const int c1 = PRIM(ch) ? 1 : 0;
            count0 = c1 * (sub0 ? 3 : 2); if (count0 > 48) count0 = 48;
            if (c1) {
                modeL = 1; aidL = AID(ch);
                offL = MODCOL_OFF + (2 + sub0) * 48;  // mcfg = 1*2 + sub0
            }
        } else if (cat0 == 0 && msk0) {
            // prim root: only row p==0 nonzero
            modeL = 2; aidL = AID(0); count0 = 1;
        }
        s_dec[0] = modeL; s_dec[1] = modeR; s_dec[2] = offL; s_dec[3] = offR;
        s_dec[4] = aidL;  s_dec[5] = aidR;  s_dec[6] = count0;
    }
    __syncthreads();

    const int p = tid >> 3, a = tid & 7;
    const int modeL = s_dec[0], modeR = s_dec[1];
    float v = 0.f;
    if (modeL == 1)       v += ws[s_dec[2] + p] * s_G[s_dec[4] * 8 + a];
    else if (modeL == 2)  { if (p == 0) v = s_G[s_dec[4] * 8 + a]; }
    if (modeR == 1)       v += ws[s_dec[3] + p] * s_G[s_dec[5] * 8 + a];
    if (a == 0 && p >= s_dec[6]) v += 8.0f;
    out[b * 384 + tid] = v;
}

extern "C" void kernel_launch(void* const* d_in, const int* in_sizes, int n_in,
                              void* d_out, int out_size, void* d_ws, size_t ws_size,
                              hipStream_t stream) {
    const int* cats = (const int*)d_in[0];
    const int* subs = (const int*)d_in[1];
    const int* mask = (const int*)d_in[2];
    const int* cl   = (const int*)d_in[3];
    const int* cr   = (const int*)d_in[4];
    const float* E   = (const float*)d_in[5];
    const float* mw1 = (const float*)d_in[6];
    const float* mb1 = (const float*)d_in[7];
    const float* mw2 = (const float*)d_in[8];
    const float* mb2 = (const float*)d_in[9];
    const float* mw3 = (const float*)d_in[10];
    const float* mb3 = (const float*)d_in[11];
    const float* cw1 = (const float*)d_in[12];
    const float* cb1 = (const float*)d_in[13];
    const float* cw2 = (const float*)d_in[14];
    const float* cb2 = (const float*)d_in[15];
    const float* cw3 = (const float*)d_in[16];
    const float* cb3 = (const float*)d_in[17];
    float* ws  = (float*)d_ws;
    float* out = (float*)d_out;
    const int B = in_sizes[0] / NNODE;

    scan_tables_a<<<225, 128, 0, stream>>>(E, mw1, mb1, mw2, mb2, mw3, mb3,
                                           cw1, cb1, cw2, cb2, ws);
    scan_tables_b<<<48 * 32, 128, 0, stream>>>(cw3, cb3, ws);
    scan_output<<<B, 384, 0, stream>>>(cats, subs, mask, cl, cr, ws, out);
}